// Round 4
// baseline (768.965 us; speedup 1.0000x reference)
//
#include <hip/hip_runtime.h>
#include <hip/hip_bf16.h>

typedef __attribute__((ext_vector_type(4))) float f32x4;
typedef __attribute__((ext_vector_type(8))) short s16x8;

#define B_ 64
#define T_ 4096
#define H_ 512
#define E_ 512
#define BM 64   // T-rows per k2 block (= context chunk)
#define NCH (T_ / BM)  // 64 chunks per batch row

__device__ __forceinline__ short b2s(float x) {
  __hip_bfloat16 h = __float2bfloat16(x);  // RNE; pairs fuse to v_cvt_pk_bf16_f32
  return __builtin_bit_cast(short, h);
}

__device__ __forceinline__ s16x8 cvt8(f32x4 a, f32x4 b) {
  s16x8 r;
  r[0] = b2s(a[0]); r[1] = b2s(a[1]); r[2] = b2s(a[2]); r[3] = b2s(a[3]);
  r[4] = b2s(b[0]); r[5] = b2s(b[1]); r[6] = b2s(b[2]); r[7] = b2s(b[3]);
  return r;
}

__device__ __forceinline__ void gload16(const float* g, float* lds) {
  __builtin_amdgcn_global_load_lds(
      (const __attribute__((address_space(1))) void*)g,
      (__attribute__((address_space(3))) void*)lds, 16, 0, 0);
}

__device__ __forceinline__ float fast_tanh(float x) {
  float e;
  asm("v_exp_f32 %0, %1" : "=v"(e) : "v"(x * 2.88539008177792681f));  // 2^(2x/ln2)
  float r;
  asm("v_rcp_f32 %0, %1" : "=v"(r) : "v"(e + 1.0f));
  return 1.0f - 2.0f * r;
}

// k0: W_e (rows 512..1023 of W_attn, [e][h]) -> Wt bf16 [h][e]
__global__ void k0_transpose(const float* __restrict__ W, unsigned short* __restrict__ Wt) {
  __shared__ float tile[16][17];
  int e0 = blockIdx.x * 16, h0 = blockIdx.y * 16;
  int tx = threadIdx.x, ty = threadIdx.y;
  tile[ty][tx] = W[(size_t)(512 + e0 + ty) * H_ + h0 + tx];
  __syncthreads();
  Wt[(size_t)(h0 + ty) * E_ + e0 + tx] = (unsigned short)b2s(tile[tx][ty]);
}

// k1: projb[b][h] = b_attn[h] + sum_e hidden[b][e] * W_attn[e][h]
__global__ __launch_bounds__(512) void k1_projb(const float* __restrict__ hidden,
                                                const float* __restrict__ W,
                                                const float* __restrict__ b_attn,
                                                float* __restrict__ projb) {
  __shared__ float hid_s[H_];
  __shared__ float part[4][128];
  const int b = blockIdx.x, hg = blockIdx.y;
  const int tid = threadIdx.x;
  const int hl = tid & 127, es = tid >> 7;
  hid_s[tid] = hidden[b * H_ + tid];
  __syncthreads();
  const int h = hg * 128 + hl;
  const float* wp = W + (size_t)(es * 128) * H_ + h;
  float s = 0.0f;
  #pragma unroll 8
  for (int e = 0; e < 128; ++e) s = fmaf(hid_s[es * 128 + e], wp[(size_t)e * H_], s);
  part[es][hl] = s;
  __syncthreads();
  if (es == 0)
    projb[b * H_ + h] = b_attn[h] + part[0][hl] + part[1][hl] + part[2][hl] + part[3][hl];
}

// k2: fused logits + chunk-softmax + partial context.
// 512 thr = 8 waves (2T x 4H); block = 64T x 512H; wave tile 32T x 128H,
// acc[2][8] = 64 AGPR -> <=128 regs/wave -> 4 waves/SIMD, 2 blocks/CU.
// A (enc fp32) double-buffered in LDS via global_load_lds (R2's proven 2-phase).
__global__ __launch_bounds__(512, 4) void k2_logits(
    const float* __restrict__ enc, const unsigned short* __restrict__ Wt,
    const float* __restrict__ projb, const float* __restrict__ vw,
    float* __restrict__ logits, float* __restrict__ mstat,
    float* __restrict__ partial) {
  __shared__ float bufA[2][BM * 64];  // 2 x 16 KiB fp32
  __shared__ float projb_s[H_];
  __shared__ float vw_s[H_];
  __shared__ float part[BM][4];
  __shared__ float lg_s[BM];
  __shared__ f32x4 comb[3][128];

  const int b = blockIdx.y;
  const int chunk = blockIdx.x;
  const int t0 = chunk * BM;
  const int tid = threadIdx.x;
  const int lane = tid & 63;
  const int w = tid >> 6;
  const int waveT = w >> 2;  // 0..1
  const int waveH = w & 3;   // 0..3
  const int lr = lane & 15;
  const int lq = lane >> 4;

  projb_s[tid] = projb[b * H_ + tid];
  vw_s[tid] = vw[tid];

  const size_t encRow0 = (size_t)b * T_ + t0;

  // stage K-slice s (64 floats/row) of the 64-row tile into bufA[bi].
  // swizzle: 16B-chunk ^= row&15 applied on SOURCE addr (LDS dest linear).
  auto stage = [&](int bi, int s) {
    #pragma unroll
    for (int j = 0; j < 2; ++j) {
      const int row = w * 8 + j * 4 + (lane >> 4);
      const int cg = (lane & 15) ^ (row & 15);
      const float* g = enc + (encRow0 + row) * (size_t)E_ + s * 64 + cg * 4;
      gload16(g, &bufA[bi][(w * 8 + j * 4) * 64]);
    }
  };

  const unsigned short* WtBase = Wt + (size_t)(waveH * 128 + lr) * E_ + lq * 8;

  stage(0, 0);
  __syncthreads();

  f32x4 acc[2][8] = {};

  for (int s = 0; s < 8; ++s) {
    if (s < 7) stage((s + 1) & 1, s + 1);  // issue next stage BEFORE compute
    const float* bp = &bufA[s & 1][0];
    #pragma unroll
    for (int sub = 0; sub < 2; ++sub) {
      s16x8 bfr[8];
      #pragma unroll
      for (int nb = 0; nb < 8; ++nb)
        bfr[nb] = *(const s16x8*)(WtBase + (size_t)nb * 16 * E_ + s * 64 + sub * 32);
      s16x8 af[2];
      #pragma unroll
      for (int a = 0; a < 2; ++a) {
        const float* rowp = bp + (waveT * 32 + a * 16 + lr) * 64;
        const int c0 = sub * 8 + lq * 2;
        f32x4 f0 = *(const f32x4*)(rowp + ((c0 ^ lr) * 4));
        f32x4 f1 = *(const f32x4*)(rowp + (((c0 + 1) ^ lr) * 4));
        af[a] = cvt8(f0, f1);
      }
      __builtin_amdgcn_s_setprio(1);
      #pragma unroll
      for (int a = 0; a < 2; ++a)
        #pragma unroll
        for (int nb = 0; nb < 8; ++nb)
          acc[a][nb] =
              __builtin_amdgcn_mfma_f32_16x16x32_bf16(af[a], bfr[nb], acc[a][nb], 0, 0, 0);
      __builtin_amdgcn_s_setprio(0);
    }
    __syncthreads();  // one drain per K-step (m97 structure; co-resident block hides it)
  }

  // ---- logits: energy = tanh(acc + projb), partial = sum_h energy * vw ----
  #pragma unroll
  for (int a = 0; a < 2; ++a) {
    #pragma unroll
    for (int j = 0; j < 4; ++j) {
      float ssum = 0.0f;
      #pragma unroll
      for (int nb = 0; nb < 8; ++nb) {
        const int h = waveH * 128 + nb * 16 + lr;  // C/D: col = lane&15
        float x = acc[a][nb][j] + projb_s[h];
        ssum += fast_tanh(x) * vw_s[h];
      }
      ssum += __shfl_xor(ssum, 1);
      ssum += __shfl_xor(ssum, 2);
      ssum += __shfl_xor(ssum, 4);
      ssum += __shfl_xor(ssum, 8);
      if (lr == 0) part[waveT * 32 + a * 16 + lq * 4 + j][waveH] = ssum;  // row = lq*4+j
    }
  }
  __syncthreads();
  if (tid < BM) {
    float l = part[tid][0] + part[tid][1] + part[tid][2] + part[tid][3];
    lg_s[tid] = l;
    logits[(size_t)b * T_ + t0 + tid] = l;
  }
  __syncthreads();

  // ---- chunk softmax numerator + partial context (enc rows are L2/L3-hot) ----
  float m_c = -1e30f;
  #pragma unroll 8
  for (int t = 0; t < BM; ++t) m_c = fmaxf(m_c, lg_s[t]);

  const int e4 = tid & 127;          // f32x4 column
  const int tg = tid >> 7;           // 0..3, 16 t-rows each
  f32x4 a4 = {};
  const float* ep = enc + (encRow0 + tg * 16) * (size_t)E_ + e4 * 4;
  #pragma unroll 4
  for (int i = 0; i < 16; ++i) {
    float p = __expf(lg_s[tg * 16 + i] - m_c);
    a4 += p * (*(const f32x4*)(ep + (size_t)i * E_));
  }
  if (tg > 0) comb[tg - 1][e4] = a4;
  __syncthreads();
  if (tg == 0) {
    f32x4 r = a4 + comb[0][e4] + comb[1][e4] + comb[2][e4];
    *(f32x4*)(partial + ((size_t)(b * NCH + chunk)) * E_ + e4 * 4) = r;
    if (tid == 0) mstat[b * NCH + chunk] = m_c;
  }
}

// k3: softmax over T per batch -> weights; also write per-b (max, Z) stats
__global__ __launch_bounds__(256) void k3_softmax(const float* __restrict__ logits,
                                                  float* __restrict__ weights,
                                                  float* __restrict__ mz) {
  __shared__ float red[4];
  const int b = blockIdx.x;
  const int tid = threadIdx.x;
  const float* lg = logits + (size_t)b * T_;
  float v[16];
  float m = -1e30f;
  #pragma unroll
  for (int i = 0; i < 16; ++i) {
    v[i] = lg[tid + i * 256];
    m = fmaxf(m, v[i]);
  }
  #pragma unroll
  for (int d = 1; d < 64; d <<= 1) m = fmaxf(m, __shfl_xor(m, d));
  if ((tid & 63) == 0) red[tid >> 6] = m;
  __syncthreads();
  m = fmaxf(fmaxf(red[0], red[1]), fmaxf(red[2], red[3]));
  __syncthreads();
  float s = 0.0f;
  #pragma unroll
  for (int i = 0; i < 16; ++i) {
    v[i] = __expf(v[i] - m);
    s += v[i];
  }
  #pragma unroll
  for (int d = 1; d < 64; d <<= 1) s += __shfl_xor(s, d);
  if ((tid & 63) == 0) red[tid >> 6] = s;
  __syncthreads();
  s = red[0] + red[1] + red[2] + red[3];
  float inv = 1.0f / s;
  #pragma unroll
  for (int i = 0; i < 16; ++i) weights[(size_t)b * T_ + tid + i * 256] = v[i] * inv;
  if (tid == 0) {
    mz[b * 2] = m;
    mz[b * 2 + 1] = s;
  }
}

// k5: context = sum_c exp(m_c - m_b) * partial[b,c,:] / Z_b
__global__ __launch_bounds__(128) void k5_ctx_final(const float* __restrict__ partial,
                                                    const float* __restrict__ mstat,
                                                    const float* __restrict__ mz,
                                                    float* __restrict__ ctx) {
  __shared__ float sc[NCH];
  const int b = blockIdx.x;
  const int tid = threadIdx.x;
  const float m_b = mz[b * 2];
  const float invZ = 1.0f / mz[b * 2 + 1];
  if (tid < NCH) sc[tid] = __expf(mstat[b * NCH + tid] - m_b);
  __syncthreads();
  const float* pp = partial + (size_t)b * NCH * E_ + tid * 4;
  f32x4 s = {};
  #pragma unroll 8
  for (int c = 0; c < NCH; ++c) s += sc[c] * (*(const f32x4*)(pp + (size_t)c * E_));
  s *= invZ;
  *(f32x4*)(ctx + (size_t)b * E_ + tid * 4) = s;
}

extern "C" void kernel_launch(void* const* d_in, const int* in_sizes, int n_in,
                              void* d_out, int out_size, void* d_ws, size_t ws_size,
                              hipStream_t stream) {
  const float* hidden = (const float*)d_in[0];
  const float* enc = (const float*)d_in[1];
  const float* W_attn = (const float*)d_in[2];
  const float* b_attn = (const float*)d_in[3];
  const float* v_w = (const float*)d_in[4];

  float* out_ctx = (float*)d_out;                  // 64*512
  float* out_w = (float*)d_out + (size_t)B_ * H_;  // 64*4096

  char* ws = (char*)d_ws;
  unsigned short* Wt = (unsigned short*)ws;      // 512 KiB
  float* projb = (float*)(ws + (512 << 10));     // 128 KiB
  float* logits = (float*)(ws + (640 << 10));    // 1 MiB
  float* mstat = (float*)(ws + (1664 << 10));    // 16 KiB (64*64 chunk maxes)
  float* mz = (float*)(ws + (1680 << 10));       // 512 B  (per-b max, Z)
  float* partial = (float*)(ws + (1696 << 10));  // 8 MiB  (64*64*512 fp32)

  k0_transpose<<<dim3(32, 32), dim3(16, 16), 0, stream>>>(W_attn, Wt);
  k1_projb<<<dim3(64, 4), 512, 0, stream>>>(hidden, W_attn, b_attn, projb);
  k2_logits<<<dim3(NCH, B_), 512, 0, stream>>>(enc, Wt, projb, v_w, logits, mstat, partial);
  k3_softmax<<<B_, 256, 0, stream>>>(logits, out_w, mz);
  k5_ctx_final<<<B_, 128, 0, stream>>>(partial, mstat, mz, out_ctx);
}

// Round 5
// 570.240 us; speedup vs baseline: 1.3485x; 1.3485x over previous
//
#include <hip/hip_runtime.h>
#include <hip/hip_bf16.h>

typedef __attribute__((ext_vector_type(4))) float f32x4;
typedef __attribute__((ext_vector_type(8))) short s16x8;

#define B_ 64
#define T_ 4096
#define H_ 512
#define E_ 512
#define BM 32          // T-rows per k2 block (= context chunk)
#define NCH (T_ / BM)  // 128 chunks per batch row

__device__ __forceinline__ short b2s(float x) {
  __hip_bfloat16 h = __float2bfloat16(x);  // RNE; pairs fuse to v_cvt_pk_bf16_f32
  return __builtin_bit_cast(short, h);
}

__device__ __forceinline__ s16x8 cvt8(f32x4 a, f32x4 b) {
  s16x8 r;
  r[0] = b2s(a[0]); r[1] = b2s(a[1]); r[2] = b2s(a[2]); r[3] = b2s(a[3]);
  r[4] = b2s(b[0]); r[5] = b2s(b[1]); r[6] = b2s(b[2]); r[7] = b2s(b[3]);
  return r;
}

__device__ __forceinline__ void gload16(const float* g, float* lds) {
  __builtin_amdgcn_global_load_lds(
      (const __attribute__((address_space(1))) void*)g,
      (__attribute__((address_space(3))) void*)lds, 16, 0, 0);
}

__device__ __forceinline__ float fast_tanh(float x) {
  float e;
  asm("v_exp_f32 %0, %1" : "=v"(e) : "v"(x * 2.88539008177792681f));  // 2^(2x/ln2)
  float r;
  asm("v_rcp_f32 %0, %1" : "=v"(r) : "v"(e + 1.0f));
  return 1.0f - 2.0f * r;
}

// k0: W_e (rows 512..1023 of W_attn, [e][h]) -> Wt bf16 [h][e]
__global__ void k0_transpose(const float* __restrict__ W, unsigned short* __restrict__ Wt) {
  __shared__ float tile[16][17];
  int e0 = blockIdx.x * 16, h0 = blockIdx.y * 16;
  int tx = threadIdx.x, ty = threadIdx.y;
  tile[ty][tx] = W[(size_t)(512 + e0 + ty) * H_ + h0 + tx];
  __syncthreads();
  Wt[(size_t)(h0 + ty) * E_ + e0 + tx] = (unsigned short)b2s(tile[tx][ty]);
}

// k1: projb[b][h] = b_attn[h] + sum_e hidden[b][e] * W_attn[e][h]
__global__ __launch_bounds__(512) void k1_projb(const float* __restrict__ hidden,
                                                const float* __restrict__ W,
                                                const float* __restrict__ b_attn,
                                                float* __restrict__ projb) {
  __shared__ float hid_s[H_];
  __shared__ float part[4][128];
  const int b = blockIdx.x, hg = blockIdx.y;
  const int tid = threadIdx.x;
  const int hl = tid & 127, es = tid >> 7;
  hid_s[tid] = hidden[b * H_ + tid];
  __syncthreads();
  const int h = hg * 128 + hl;
  const float* wp = W + (size_t)(es * 128) * H_ + h;
  float s = 0.0f;
  #pragma unroll 8
  for (int e = 0; e < 128; ++e) s = fmaf(hid_s[es * 128 + e], wp[(size_t)e * H_], s);
  part[es][hl] = s;
  __syncthreads();
  if (es == 0)
    projb[b * H_ + h] = b_attn[h] + part[0][hl] + part[1][hl] + part[2][hl] + part[3][hl];
}

// k2: fused logits + chunk-softmax + partial context.
// 256 thr = 4 waves; block = 32T x 512H; wave tile 32T x 128H (waveH = w).
// acc[2][8] = 64 AGPR; launch_bounds(256,3): 170-reg cap, ~140 needed -> no
// spill, 3 blocks/CU. A (enc fp32) double-buffered via global_load_lds.
__global__ __launch_bounds__(256, 3) void k2_logits(
    const float* __restrict__ enc, const unsigned short* __restrict__ Wt,
    const float* __restrict__ projb, const float* __restrict__ vw,
    float* __restrict__ logits, float* __restrict__ mstat,
    float* __restrict__ partial) {
  __shared__ float bufA[2][BM * 64];  // 2 x 8 KiB fp32
  __shared__ float projb_s[H_];
  __shared__ float vw_s[H_];
  __shared__ float part[BM][4];
  __shared__ float lg_s[BM];
  __shared__ f32x4 comb[128];

  const int b = blockIdx.y;
  const int chunk = blockIdx.x;
  const int t0 = chunk * BM;
  const int tid = threadIdx.x;
  const int lane = tid & 63;
  const int w = tid >> 6;  // wave id = H-slice (0..3)
  const int lr = lane & 15;
  const int lq = lane >> 4;

  projb_s[tid] = projb[b * H_ + tid];
  projb_s[tid + 256] = projb[b * H_ + tid + 256];
  vw_s[tid] = vw[tid];
  vw_s[tid + 256] = vw[tid + 256];

  const size_t encRow0 = (size_t)b * T_ + t0;

  // stage K-slice s (64 floats/row) of the 32-row tile into bufA[bi].
  // swizzle: 16B-chunk ^= row&15 on SOURCE addr (LDS dest linear, rule #21).
  auto stage = [&](int bi, int s) {
    #pragma unroll
    for (int j = 0; j < 2; ++j) {
      const int row = w * 8 + j * 4 + lq;
      const int cg = lr ^ (row & 15);
      const float* g = enc + (encRow0 + row) * (size_t)E_ + s * 64 + cg * 4;
      gload16(g, &bufA[bi][(w * 8 + j * 4) * 64]);
    }
  };

  const unsigned short* WtBase = Wt + (size_t)(w * 128 + lr) * E_ + lq * 8;

  stage(0, 0);
  __syncthreads();

  f32x4 acc[2][8] = {};

  for (int s = 0; s < 8; ++s) {
    if (s < 7) stage((s + 1) & 1, s + 1);  // issue next stage BEFORE compute
    const float* bp = &bufA[s & 1][0];
    #pragma unroll
    for (int sub = 0; sub < 2; ++sub) {
      s16x8 bfr[8];
      #pragma unroll
      for (int nb = 0; nb < 8; ++nb)
        bfr[nb] = *(const s16x8*)(WtBase + (size_t)nb * 16 * E_ + s * 64 + sub * 32);
      s16x8 af[2];
      #pragma unroll
      for (int a = 0; a < 2; ++a) {
        const float* rowp = bp + (a * 16 + lr) * 64;
        const int c0 = sub * 8 + lq * 2;
        f32x4 f0 = *(const f32x4*)(rowp + ((c0 ^ lr) * 4));
        f32x4 f1 = *(const f32x4*)(rowp + (((c0 + 1) ^ lr) * 4));
        af[a] = cvt8(f0, f1);
      }
      __builtin_amdgcn_s_setprio(1);
      #pragma unroll
      for (int a = 0; a < 2; ++a)
        #pragma unroll
        for (int nb = 0; nb < 8; ++nb)
          acc[a][nb] =
              __builtin_amdgcn_mfma_f32_16x16x32_bf16(af[a], bfr[nb], acc[a][nb], 0, 0, 0);
      __builtin_amdgcn_s_setprio(0);
    }
    __syncthreads();  // one drain per K-step; co-resident blocks hide it (m114)
  }

  // ---- logits: energy = tanh(acc + projb), partial = sum_h energy * vw ----
  #pragma unroll
  for (int a = 0; a < 2; ++a) {
    #pragma unroll
    for (int j = 0; j < 4; ++j) {
      float ssum = 0.0f;
      #pragma unroll
      for (int nb = 0; nb < 8; ++nb) {
        const int h = w * 128 + nb * 16 + lr;  // C/D: col = lane&15
        float x = acc[a][nb][j] + projb_s[h];
        ssum += fast_tanh(x) * vw_s[h];
      }
      ssum += __shfl_xor(ssum, 1);
      ssum += __shfl_xor(ssum, 2);
      ssum += __shfl_xor(ssum, 4);
      ssum += __shfl_xor(ssum, 8);
      if (lr == 0) part[a * 16 + lq * 4 + j][w] = ssum;  // C/D: row = lq*4+j
    }
  }
  __syncthreads();
  if (tid < BM) {
    float l = part[tid][0] + part[tid][1] + part[tid][2] + part[tid][3];
    lg_s[tid] = l;
    logits[(size_t)b * T_ + t0 + tid] = l;
  }
  __syncthreads();

  // ---- chunk softmax numerator + partial context (tile is L2-hot) ----
  float m_c = -1e30f;
  #pragma unroll
  for (int t = 0; t < BM; ++t) m_c = fmaxf(m_c, lg_s[t]);

  const int e4 = tid & 127;  // f32x4 column
  const int tg = tid >> 7;   // 0..1, 16 t-rows each
  f32x4 a4 = {};
  const float* ep = enc + (encRow0 + tg * 16) * (size_t)E_ + e4 * 4;
  #pragma unroll 4
  for (int i = 0; i < 16; ++i) {
    float p = __expf(lg_s[tg * 16 + i] - m_c);
    a4 += p * (*(const f32x4*)(ep + (size_t)i * E_));
  }
  if (tg == 1) comb[e4] = a4;
  __syncthreads();
  if (tg == 0) {
    f32x4 r = a4 + comb[e4];
    *(f32x4*)(partial + ((size_t)(b * NCH + chunk)) * E_ + e4 * 4) = r;
    if (tid == 0) mstat[b * NCH + chunk] = m_c;
  }
}

// k3: softmax over T per batch -> weights; also per-b (max, Z)
__global__ __launch_bounds__(256) void k3_softmax(const float* __restrict__ logits,
                                                  float* __restrict__ weights,
                                                  float* __restrict__ mz) {
  __shared__ float red[4];
  const int b = blockIdx.x;
  const int tid = threadIdx.x;
  const float* lg = logits + (size_t)b * T_;
  float v[16];
  float m = -1e30f;
  #pragma unroll
  for (int i = 0; i < 16; ++i) {
    v[i] = lg[tid + i * 256];
    m = fmaxf(m, v[i]);
  }
  #pragma unroll
  for (int d = 1; d < 64; d <<= 1) m = fmaxf(m, __shfl_xor(m, d));
  if ((tid & 63) == 0) red[tid >> 6] = m;
  __syncthreads();
  m = fmaxf(fmaxf(red[0], red[1]), fmaxf(red[2], red[3]));
  __syncthreads();
  float s = 0.0f;
  #pragma unroll
  for (int i = 0; i < 16; ++i) {
    v[i] = __expf(v[i] - m);
    s += v[i];
  }
  #pragma unroll
  for (int d = 1; d < 64; d <<= 1) s += __shfl_xor(s, d);
  if ((tid & 63) == 0) red[tid >> 6] = s;
  __syncthreads();
  s = red[0] + red[1] + red[2] + red[3];
  float inv = 1.0f / s;
  #pragma unroll
  for (int i = 0; i < 16; ++i) weights[(size_t)b * T_ + tid + i * 256] = v[i] * inv;
  if (tid == 0) {
    mz[b * 2] = m;
    mz[b * 2 + 1] = s;
  }
}

// k5: context = sum_c exp(m_c - m_b) * partial[b,c,:] / Z_b
__global__ __launch_bounds__(128) void k5_ctx_final(const float* __restrict__ partial,
                                                    const float* __restrict__ mstat,
                                                    const float* __restrict__ mz,
                                                    float* __restrict__ ctx) {
  __shared__ float sc[NCH];
  const int b = blockIdx.x;
  const int tid = threadIdx.x;
  const float m_b = mz[b * 2];
  const float invZ = 1.0f / mz[b * 2 + 1];
  sc[tid] = __expf(mstat[b * NCH + tid] - m_b);
  sc[tid + 128] = __expf(mstat[b * NCH + tid + 128] - m_b);
  __syncthreads();
  const float* pp = partial + (size_t)b * NCH * E_ + tid * 4;
  f32x4 s = {};
  #pragma unroll 8
  for (int c = 0; c < NCH; ++c) s += sc[c] * (*(const f32x4*)(pp + (size_t)c * E_));
  s *= invZ;
  *(f32x4*)(ctx + (size_t)b * E_ + tid * 4) = s;
}

extern "C" void kernel_launch(void* const* d_in, const int* in_sizes, int n_in,
                              void* d_out, int out_size, void* d_ws, size_t ws_size,
                              hipStream_t stream) {
  const float* hidden = (const float*)d_in[0];
  const float* enc = (const float*)d_in[1];
  const float* W_attn = (const float*)d_in[2];
  const float* b_attn = (const float*)d_in[3];
  const float* v_w = (const float*)d_in[4];

  float* out_ctx = (float*)d_out;                  // 64*512
  float* out_w = (float*)d_out + (size_t)B_ * H_;  // 64*4096

  char* ws = (char*)d_ws;
  unsigned short* Wt = (unsigned short*)ws;      // 512 KiB
  float* projb = (float*)(ws + (512 << 10));     // 128 KiB
  float* logits = (float*)(ws + (640 << 10));    // 1 MiB
  float* mstat = (float*)(ws + (1664 << 10));    // 32 KiB (64*128 chunk maxes)
  float* mz = (float*)(ws + (1700 << 10));       // 512 B  (per-b max, Z)
  float* partial = (float*)(ws + (1728 << 10));  // 16 MiB (64*128*512 fp32)

  k0_transpose<<<dim3(32, 32), dim3(16, 16), 0, stream>>>(W_attn, Wt);
  k1_projb<<<dim3(64, 4), 512, 0, stream>>>(hidden, W_attn, b_attn, projb);
  k2_logits<<<dim3(NCH, B_), 256, 0, stream>>>(enc, Wt, projb, v_w, logits, mstat, partial);
  k3_softmax<<<B_, 256, 0, stream>>>(logits, out_w, mz);
  k5_ctx_final<<<B_, 128, 0, stream>>>(partial, mstat, mz, out_ctx);
}

// Round 6
// 378.032 us; speedup vs baseline: 2.0341x; 1.5084x over previous
//
#include <hip/hip_runtime.h>
#include <hip/hip_bf16.h>

typedef __attribute__((ext_vector_type(4))) float f32x4;
typedef __attribute__((ext_vector_type(8))) short s16x8;

#define B_ 64
#define T_ 4096
#define H_ 512
#define E_ 512
#define BM 64          // T-rows per k2 block (= context chunk)
#define NCH (T_ / BM)  // 64 chunks per batch row

__device__ __forceinline__ short b2s(float x) {
  __hip_bfloat16 h = __float2bfloat16(x);  // RNE; pairs fuse to v_cvt_pk_bf16_f32
  return __builtin_bit_cast(short, h);
}

__device__ __forceinline__ s16x8 cvt8(f32x4 a, f32x4 b) {
  s16x8 r;
  r[0] = b2s(a[0]); r[1] = b2s(a[1]); r[2] = b2s(a[2]); r[3] = b2s(a[3]);
  r[4] = b2s(b[0]); r[5] = b2s(b[1]); r[6] = b2s(b[2]); r[7] = b2s(b[3]);
  return r;
}

__device__ __forceinline__ void gload16s(const unsigned short* g, unsigned short* lds) {
  // async global->LDS 16B/lane; dest = wave-uniform base + lane*16 (linear)
  __builtin_amdgcn_global_load_lds(
      (const __attribute__((address_space(1))) void*)g,
      (__attribute__((address_space(3))) void*)lds, 16, 0, 0);
}

__device__ __forceinline__ float fast_tanh(float x) {
  float e;
  asm("v_exp_f32 %0, %1" : "=v"(e) : "v"(x * 2.88539008177792681f));  // 2^(2x/ln2)
  float r;
  asm("v_rcp_f32 %0, %1" : "=v"(r) : "v"(e + 1.0f));
  return 1.0f - 2.0f * r;
}

// k0: W_e (rows 512..1023 of W_attn, [e][h]) -> Wt bf16 [h][e]
__global__ void k0_transpose(const float* __restrict__ W, unsigned short* __restrict__ Wt) {
  __shared__ float tile[16][17];
  int e0 = blockIdx.x * 16, h0 = blockIdx.y * 16;
  int tx = threadIdx.x, ty = threadIdx.y;
  tile[ty][tx] = W[(size_t)(512 + e0 + ty) * H_ + h0 + tx];
  __syncthreads();
  Wt[(size_t)(h0 + ty) * E_ + e0 + tx] = (unsigned short)b2s(tile[tx][ty]);
}

// k1: projb[b][h] = b_attn[h] + sum_e hidden[b][e] * W_attn[e][h]
__global__ __launch_bounds__(512) void k1_projb(const float* __restrict__ hidden,
                                                const float* __restrict__ W,
                                                const float* __restrict__ b_attn,
                                                float* __restrict__ projb) {
  __shared__ float hid_s[H_];
  __shared__ float part[4][128];
  const int b = blockIdx.x, hg = blockIdx.y;
  const int tid = threadIdx.x;
  const int hl = tid & 127, es = tid >> 7;
  hid_s[tid] = hidden[b * H_ + tid];
  __syncthreads();
  const int h = hg * 128 + hl;
  const float* wp = W + (size_t)(es * 128) * H_ + h;
  float s = 0.0f;
  #pragma unroll 8
  for (int e = 0; e < 128; ++e) s = fmaf(hid_s[es * 128 + e], wp[(size_t)e * H_], s);
  part[es][hl] = s;
  __syncthreads();
  if (es == 0)
    projb[b * H_ + h] = b_attn[h] + part[0][hl] + part[1][hl] + part[2][hl] + part[3][hl];
}

// k2: fused logits + chunk-softmax + partial context.
// 512 thr = 8 waves (1T x 8H); block = 64T x 512H; wave tile 64T x 64H,
// acc[4][4] = 64 AGPR. BOTH operands LDS-resident per K-step (BK=64):
//   Wt (bf16) via global_load_lds (zero-VGPR), double-buffered, 64 KB/step
//   A (enc)   via global->reg->cvt(bf16)->ds_write (T14 split), 8 KB/step
// All staging issued at step top, consumed next step -> barrier drain ~free.
// XOR swizzle chunk^=(row&7) on both tiles (Wt: pre-swizzled source, rule #21).
__global__ __launch_bounds__(512, 2) void k2_logits(
    const float* __restrict__ enc, const unsigned short* __restrict__ Wt,
    const float* __restrict__ projb, const float* __restrict__ vw,
    float* __restrict__ logits, float* __restrict__ mstat,
    float* __restrict__ partial) {
  __shared__ unsigned short wt_s[2][H_ * 64];  // 2 x 64 KiB
  __shared__ unsigned short a_s[2][BM * 64];   // 2 x 8 KiB
  __shared__ float projb_s[H_];
  __shared__ float vw_s[H_];
  __shared__ float part[BM][8];
  __shared__ float lg_s[BM];
  __shared__ f32x4 comb[3][128];

  const int b = blockIdx.y;
  const int chunk = blockIdx.x;
  const int t0 = chunk * BM;
  const int tid = threadIdx.x;
  const int lane = tid & 63;
  const int w = tid >> 6;  // wave id = H-slice (0..7)
  const int lr = lane & 15;
  const int lq = lane >> 4;

  projb_s[tid] = projb[b * H_ + tid];
  vw_s[tid] = vw[tid];

  const size_t row0 = (size_t)b * T_ + t0;

  // stage Wt K-slice s into wt_s[bi]: 8 gload_lds/thread, linear LDS dest,
  // source chunk pre-swizzled so read-side XOR recovers it.
  auto stageWt = [&](int bi, int s) {
    #pragma unroll
    for (int j = 0; j < 8; ++j) {
      const int slot = j * 512 + tid;
      const int h = slot >> 3, ch = slot & 7;
      const unsigned short* src = Wt + (size_t)h * E_ + s * 64 + ((ch ^ (h & 7)) << 3);
      gload16s(src, &wt_s[bi][(size_t)(j * 512 + w * 64) * 8]);
    }
  };

  // A staging geometry: 1 slot (16B bf16 = 8 elems) per thread
  const int tA = tid >> 3, chA = tid & 7;
  const float* aSrc = enc + (row0 + tA) * (size_t)E_ + (chA << 3);
  const int aDst = tA * 64 + ((chA ^ (tA & 7)) << 3);

  // prologue: stage step 0
  stageWt(0, 0);
  f32x4 v0 = *(const f32x4*)(aSrc);
  f32x4 v1 = *(const f32x4*)(aSrc + 4);
  *(s16x8*)&a_s[0][aDst] = cvt8(v0, v1);
  __syncthreads();

  f32x4 acc[4][4] = {};

  for (int s = 0; s < 8; ++s) {
    const int cur = s & 1, nxt = cur ^ 1;
    if (s < 7) {
      stageWt(nxt, s + 1);                          // zero-VGPR async
      v0 = *(const f32x4*)(aSrc + (s + 1) * 64);    // A loads issued early
      v1 = *(const f32x4*)(aSrc + (s + 1) * 64 + 4);
    }
    #pragma unroll
    for (int sub = 0; sub < 2; ++sub) {
      const int ch = sub * 4 + lq;
      s16x8 bfr[4], af[4];
      #pragma unroll
      for (int nb = 0; nb < 4; ++nb) {
        const int h = w * 64 + nb * 16 + lr;
        bfr[nb] = *(const s16x8*)&wt_s[cur][h * 64 + ((ch ^ (h & 7)) << 3)];
      }
      #pragma unroll
      for (int a = 0; a < 4; ++a) {
        const int t = a * 16 + lr;
        af[a] = *(const s16x8*)&a_s[cur][t * 64 + ((ch ^ (t & 7)) << 3)];
      }
      __builtin_amdgcn_s_setprio(1);
      #pragma unroll
      for (int a = 0; a < 4; ++a)
        #pragma unroll
        for (int nb = 0; nb < 4; ++nb)
          acc[a][nb] =
              __builtin_amdgcn_mfma_f32_16x16x32_bf16(af[a], bfr[nb], acc[a][nb], 0, 0, 0);
      __builtin_amdgcn_s_setprio(0);
    }
    if (s < 7) *(s16x8*)&a_s[nxt][aDst] = cvt8(v0, v1);  // write-late
    __syncthreads();  // staging had the whole step to land -> ~free drain
  }

  // ---- logits: energy = tanh(acc + projb), partial = sum_h energy * vw ----
  #pragma unroll
  for (int a = 0; a < 4; ++a) {
    #pragma unroll
    for (int j = 0; j < 4; ++j) {
      float ssum = 0.0f;
      #pragma unroll
      for (int nb = 0; nb < 4; ++nb) {
        const int h = w * 64 + nb * 16 + lr;  // C/D: col = lane&15
        float x = acc[a][nb][j] + projb_s[h];
        ssum += fast_tanh(x) * vw_s[h];
      }
      ssum += __shfl_xor(ssum, 1);
      ssum += __shfl_xor(ssum, 2);
      ssum += __shfl_xor(ssum, 4);
      ssum += __shfl_xor(ssum, 8);
      if (lr == 0) part[a * 16 + lq * 4 + j][w] = ssum;  // C/D: row = lq*4+j
    }
  }
  __syncthreads();
  if (tid < BM) {
    float l = part[tid][0] + part[tid][1] + part[tid][2] + part[tid][3] +
              part[tid][4] + part[tid][5] + part[tid][6] + part[tid][7];
    lg_s[tid] = l;
    logits[(size_t)b * T_ + t0 + tid] = l;
  }
  __syncthreads();

  // ---- chunk softmax numerator + partial context (tile rows are L2-hot) ----
  float m_c = -1e30f;
  #pragma unroll 8
  for (int t = 0; t < BM; ++t) m_c = fmaxf(m_c, lg_s[t]);

  const int e4 = tid & 127;  // f32x4 column
  const int tg = tid >> 7;   // 0..3, 16 t-rows each
  f32x4 a4 = {};
  const float* ep = enc + (row0 + tg * 16) * (size_t)E_ + e4 * 4;
  #pragma unroll 4
  for (int i = 0; i < 16; ++i) {
    float p = __expf(lg_s[tg * 16 + i] - m_c);
    a4 += p * (*(const f32x4*)(ep + (size_t)i * E_));
  }
  if (tg > 0) comb[tg - 1][e4] = a4;
  __syncthreads();
  if (tg == 0) {
    f32x4 r = a4 + comb[0][e4] + comb[1][e4] + comb[2][e4];
    *(f32x4*)(partial + ((size_t)(b * NCH + chunk)) * E_ + e4 * 4) = r;
    if (tid == 0) mstat[b * NCH + chunk] = m_c;
  }
}

// k3: softmax over T per batch -> weights; also per-b (max, Z)
__global__ __launch_bounds__(256) void k3_softmax(const float* __restrict__ logits,
                                                  float* __restrict__ weights,
                                                  float* __restrict__ mz) {
  __shared__ float red[4];
  const int b = blockIdx.x;
  const int tid = threadIdx.x;
  const float* lg = logits + (size_t)b * T_;
  float v[16];
  float m = -1e30f;
  #pragma unroll
  for (int i = 0; i < 16; ++i) {
    v[i] = lg[tid + i * 256];
    m = fmaxf(m, v[i]);
  }
  #pragma unroll
  for (int d = 1; d < 64; d <<= 1) m = fmaxf(m, __shfl_xor(m, d));
  if ((tid & 63) == 0) red[tid >> 6] = m;
  __syncthreads();
  m = fmaxf(fmaxf(red[0], red[1]), fmaxf(red[2], red[3]));
  __syncthreads();
  float s = 0.0f;
  #pragma unroll
  for (int i = 0; i < 16; ++i) {
    v[i] = __expf(v[i] - m);
    s += v[i];
  }
  #pragma unroll
  for (int d = 1; d < 64; d <<= 1) s += __shfl_xor(s, d);
  if ((tid & 63) == 0) red[tid >> 6] = s;
  __syncthreads();
  s = red[0] + red[1] + red[2] + red[3];
  float inv = 1.0f / s;
  #pragma unroll
  for (int i = 0; i < 16; ++i) weights[(size_t)b * T_ + tid + i * 256] = v[i] * inv;
  if (tid == 0) {
    mz[b * 2] = m;
    mz[b * 2 + 1] = s;
  }
}

// k5: context = sum_c exp(m_c - m_b) * partial[b,c,:] / Z_b
__global__ __launch_bounds__(128) void k5_ctx_final(const float* __restrict__ partial,
                                                    const float* __restrict__ mstat,
                                                    const float* __restrict__ mz,
                                                    float* __restrict__ ctx) {
  __shared__ float sc[NCH];
  const int b = blockIdx.x;
  const int tid = threadIdx.x;
  const float m_b = mz[b * 2];
  const float invZ = 1.0f / mz[b * 2 + 1];
  if (tid < NCH) sc[tid] = __expf(mstat[b * NCH + tid] - m_b);
  __syncthreads();
  const float* pp = partial + (size_t)b * NCH * E_ + tid * 4;
  f32x4 s = {};
  #pragma unroll 8
  for (int c = 0; c < NCH; ++c) s += sc[c] * (*(const f32x4*)(pp + (size_t)c * E_));
  s *= invZ;
  *(f32x4*)(ctx + (size_t)b * E_ + tid * 4) = s;
}

extern "C" void kernel_launch(void* const* d_in, const int* in_sizes, int n_in,
                              void* d_out, int out_size, void* d_ws, size_t ws_size,
                              hipStream_t stream) {
  const float* hidden = (const float*)d_in[0];
  const float* enc = (const float*)d_in[1];
  const float* W_attn = (const float*)d_in[2];
  const float* b_attn = (const float*)d_in[3];
  const float* v_w = (const float*)d_in[4];

  float* out_ctx = (float*)d_out;                  // 64*512
  float* out_w = (float*)d_out + (size_t)B_ * H_;  // 64*4096

  char* ws = (char*)d_ws;
  unsigned short* Wt = (unsigned short*)ws;      // 512 KiB
  float* projb = (float*)(ws + (512 << 10));     // 128 KiB
  float* logits = (float*)(ws + (640 << 10));    // 1 MiB
  float* mstat = (float*)(ws + (1664 << 10));    // 16 KiB (64*64 chunk maxes)
  float* mz = (float*)(ws + (1700 << 10));       // 512 B  (per-b max, Z)
  float* partial = (float*)(ws + (1728 << 10));  // 8 MiB  (64*64*512 fp32)

  k0_transpose<<<dim3(32, 32), dim3(16, 16), 0, stream>>>(W_attn, Wt);
  k1_projb<<<dim3(64, 4), 512, 0, stream>>>(hidden, W_attn, b_attn, projb);
  k2_logits<<<dim3(NCH, B_), 512, 0, stream>>>(enc, Wt, projb, v_w, logits, mstat, partial);
  k3_softmax<<<B_, 256, 0, stream>>>(logits, out_w, mz);
  k5_ctx_final<<<B_, 128, 0, stream>>>(partial, mstat, mz, out_ctx);
}

// Round 7
// 373.366 us; speedup vs baseline: 2.0595x; 1.0125x over previous
//
#include <hip/hip_runtime.h>
#include <hip/hip_bf16.h>

typedef __attribute__((ext_vector_type(4))) float f32x4;
typedef __attribute__((ext_vector_type(8))) short s16x8;

#define B_ 64
#define T_ 4096
#define H_ 512
#define E_ 512
#define BM 64          // T-rows per k2 block (= context chunk)
#define NCH (T_ / BM)  // 64 chunks per batch row
#define AROW 40        // A-LDS row pitch in ushorts (80 B: spreads bank quads)

__device__ __forceinline__ short b2s(float x) {
  __hip_bfloat16 h = __float2bfloat16(x);  // RNE; pairs fuse to v_cvt_pk_bf16_f32
  return __builtin_bit_cast(short, h);
}

__device__ __forceinline__ s16x8 cvt8(f32x4 a, f32x4 b) {
  s16x8 r;
  r[0] = b2s(a[0]); r[1] = b2s(a[1]); r[2] = b2s(a[2]); r[3] = b2s(a[3]);
  r[4] = b2s(b[0]); r[5] = b2s(b[1]); r[6] = b2s(b[2]); r[7] = b2s(b[3]);
  return r;
}

__device__ __forceinline__ float fast_tanh(float x) {
  float e;
  asm("v_exp_f32 %0, %1" : "=v"(e) : "v"(x * 2.88539008177792681f));  // 2^(2x/ln2)
  float r;
  asm("v_rcp_f32 %0, %1" : "=v"(r) : "v"(e + 1.0f));
  return 1.0f - 2.0f * r;
}

// k0: W_e (rows 512..1023 of W_attn, [e][h]) -> Wt bf16 [h][e]
__global__ void k0_transpose(const float* __restrict__ W, unsigned short* __restrict__ Wt) {
  __shared__ float tile[16][17];
  int e0 = blockIdx.x * 16, h0 = blockIdx.y * 16;
  int tx = threadIdx.x, ty = threadIdx.y;
  tile[ty][tx] = W[(size_t)(512 + e0 + ty) * H_ + h0 + tx];
  __syncthreads();
  Wt[(size_t)(h0 + ty) * E_ + e0 + tx] = (unsigned short)b2s(tile[tx][ty]);
}

// k1: projb[b][h] = b_attn[h] + sum_e hidden[b][e] * W_attn[e][h]
__global__ __launch_bounds__(512) void k1_projb(const float* __restrict__ hidden,
                                                const float* __restrict__ W,
                                                const float* __restrict__ b_attn,
                                                float* __restrict__ projb) {
  __shared__ float hid_s[H_];
  __shared__ float part[4][128];
  const int b = blockIdx.x, hg = blockIdx.y;
  const int tid = threadIdx.x;
  const int hl = tid & 127, es = tid >> 7;
  hid_s[tid] = hidden[b * H_ + tid];
  __syncthreads();
  const int h = hg * 128 + hl;
  const float* wp = W + (size_t)(es * 128) * H_ + h;
  float s = 0.0f;
  #pragma unroll 8
  for (int e = 0; e < 128; ++e) s = fmaf(hid_s[es * 128 + e], wp[(size_t)e * H_], s);
  part[es][hl] = s;
  __syncthreads();
  if (es == 0)
    projb[b * H_ + h] = b_attn[h] + part[0][hl] + part[1][hl] + part[2][hl] + part[3][hl];
}

// k2: fused logits + chunk-softmax + partial context.
// 256 thr = 4 waves; block = 64T x 512H; wave tile 64T x 128H, acc[4][8]=128 AGPR.
// B (Wt) lives in REGISTERS, double-buffered, prefetched 1 K-step ahead from
// L2-resident Wt (512 KB). A (enc) prefetched 2 K-steps ahead global->reg,
// cvt to bf16, ds_write into pad-80B LDS tile (double-buffered, 5 KB each).
// Raw s_barrier + lgkmcnt(0) only: reg-dest loads stay in flight across the
// barrier; every vmcnt the compiler inserts is counted (>=10 outstanding).
__global__ __launch_bounds__(256, 2) void k2_logits(
    const float* __restrict__ enc, const unsigned short* __restrict__ Wt,
    const float* __restrict__ projb, const float* __restrict__ vw,
    float* __restrict__ logits, float* __restrict__ mstat,
    float* __restrict__ partial) {
  __shared__ unsigned short a_s[2][BM * AROW];  // 2 x 5 KiB
  __shared__ float projb_s[H_];
  __shared__ float vw_s[H_];
  __shared__ float part[BM][4];
  __shared__ float lg_s[BM];
  __shared__ f32x4 comb[128];

  const int b = blockIdx.y;
  const int chunk = blockIdx.x;
  const int t0 = chunk * BM;
  const int tid = threadIdx.x;
  const int lane = tid & 63;
  const int w = tid >> 6;  // wave id = H-slice (0..3)
  const int lr = lane & 15;
  const int lq = lane >> 4;

  projb_s[tid] = projb[b * H_ + tid];
  projb_s[tid + 256] = projb[b * H_ + tid + 256];
  vw_s[tid] = vw[tid];
  vw_s[tid + 256] = vw[tid + 256];

  const size_t row0 = (size_t)b * T_ + t0;

  // A staging geometry: thread -> (row ra, 16B chunk ca); 32 B fp32 per step
  const int ra = tid >> 2;
  const int ca = tid & 3;
  const float* aBase = enc + (row0 + ra) * (size_t)E_ + ca * 8;
  const int aDst = ra * AROW + ca * 8;

  // B fragment base: lane holds Wt row h = w*128 + nb*16 + lr, k-octet lq
  const unsigned short* wtB = Wt + (size_t)(w * 128 + lr) * E_ + lq * 8;

  s16x8 bA[8], bB[8];
  f32x4 eE0, eE1, eO0, eO1;

  // ---- prologue ----
  f32x4 p0 = *(const f32x4*)(aBase);
  f32x4 p1 = *(const f32x4*)(aBase + 4);
  eO0 = *(const f32x4*)(aBase + 32);  // A(1), consumed at even step 0
  eO1 = *(const f32x4*)(aBase + 36);
  #pragma unroll
  for (int nb = 0; nb < 8; ++nb) bA[nb] = *(const s16x8*)(wtB + (size_t)nb * 16 * E_);
  *(s16x8*)&a_s[0][aDst] = cvt8(p0, p1);  // A(0) -> buf0
  asm volatile("s_waitcnt lgkmcnt(0)" ::: "memory");
  __builtin_amdgcn_s_barrier();
  __builtin_amdgcn_sched_barrier(0);

  f32x4 acc[4][8] = {};

  #pragma unroll
  for (int p = 0; p < 8; ++p) {
    const int s = 2 * p;
    // ======== even step s: reads a_s[0], MFMA with bA ========
    if (p < 7) {  // issue A(s+2) -> even set
      eE0 = *(const f32x4*)(aBase + (s + 2) * 32);
      eE1 = *(const f32x4*)(aBase + (s + 2) * 32 + 4);
    }
    #pragma unroll
    for (int nb = 0; nb < 8; ++nb)  // issue B(s+1) -> bB
      bB[nb] = *(const s16x8*)(wtB + (size_t)nb * 16 * E_ + (s + 1) * 32);
    {
      s16x8 af[4];
      #pragma unroll
      for (int a = 0; a < 4; ++a)
        af[a] = *(const s16x8*)&a_s[0][(a * 16 + lr) * AROW + lq * 8];
      __builtin_amdgcn_s_setprio(1);
      #pragma unroll
      for (int a = 0; a < 4; ++a)
        #pragma unroll
        for (int nb = 0; nb < 8; ++nb)
          acc[a][nb] =
              __builtin_amdgcn_mfma_f32_16x16x32_bf16(af[a], bA[nb], acc[a][nb], 0, 0, 0);
      __builtin_amdgcn_s_setprio(0);
    }
    *(s16x8*)&a_s[1][aDst] = cvt8(eO0, eO1);  // A(s+1) -> buf1
    asm volatile("s_waitcnt lgkmcnt(0)" ::: "memory");
    __builtin_amdgcn_s_barrier();
    __builtin_amdgcn_sched_barrier(0);

    // ======== odd step s+1: reads a_s[1], MFMA with bB ========
    if (p < 7) {  // issue A(s+3) -> odd set, B(s+2) -> bA
      eO0 = *(const f32x4*)(aBase + (s + 3) * 32);
      eO1 = *(const f32x4*)(aBase + (s + 3) * 32 + 4);
      #pragma unroll
      for (int nb = 0; nb < 8; ++nb)
        bA[nb] = *(const s16x8*)(wtB + (size_t)nb * 16 * E_ + (s + 2) * 32);
    }
    {
      s16x8 af[4];
      #pragma unroll
      for (int a = 0; a < 4; ++a)
        af[a] = *(const s16x8*)&a_s[1][(a * 16 + lr) * AROW + lq * 8];
      __builtin_amdgcn_s_setprio(1);
      #pragma unroll
      for (int a = 0; a < 4; ++a)
        #pragma unroll
        for (int nb = 0; nb < 8; ++nb)
          acc[a][nb] =
              __builtin_amdgcn_mfma_f32_16x16x32_bf16(af[a], bB[nb], acc[a][nb], 0, 0, 0);
      __builtin_amdgcn_s_setprio(0);
    }
    if (p < 7) {
      *(s16x8*)&a_s[0][aDst] = cvt8(eE0, eE1);  // A(s+2) -> buf0
      asm volatile("s_waitcnt lgkmcnt(0)" ::: "memory");
      __builtin_amdgcn_s_barrier();
      __builtin_amdgcn_sched_barrier(0);
    }
  }

  // ---- logits: energy = tanh(acc + projb), partial = sum_h energy * vw ----
  #pragma unroll
  for (int a = 0; a < 4; ++a) {
    #pragma unroll
    for (int j = 0; j < 4; ++j) {
      float ssum = 0.0f;
      #pragma unroll
      for (int nb = 0; nb < 8; ++nb) {
        const int h = w * 128 + nb * 16 + lr;  // C/D: col = lane&15
        float x = acc[a][nb][j] + projb_s[h];
        ssum += fast_tanh(x) * vw_s[h];
      }
      ssum += __shfl_xor(ssum, 1);
      ssum += __shfl_xor(ssum, 2);
      ssum += __shfl_xor(ssum, 4);
      ssum += __shfl_xor(ssum, 8);
      if (lr == 0) part[a * 16 + lq * 4 + j][w] = ssum;  // C/D: row = lq*4+j
    }
  }
  __syncthreads();
  if (tid < BM) {
    float l = part[tid][0] + part[tid][1] + part[tid][2] + part[tid][3];
    lg_s[tid] = l;
    logits[(size_t)b * T_ + t0 + tid] = l;
  }
  __syncthreads();

  // ---- chunk softmax numerator + partial context (tile rows are L2-hot) ----
  float m_c = -1e30f;
  #pragma unroll 8
  for (int t = 0; t < BM; ++t) m_c = fmaxf(m_c, lg_s[t]);

  const int e4 = tid & 127;  // f32x4 column
  const int tg = tid >> 7;   // 0..1, 32 t-rows each
  f32x4 a4 = {};
  const float* ep = enc + (row0 + tg * 32) * (size_t)E_ + e4 * 4;
  #pragma unroll 4
  for (int i = 0; i < 32; ++i) {
    float pw = __expf(lg_s[tg * 32 + i] - m_c);
    a4 += pw * (*(const f32x4*)(ep + (size_t)i * E_));
  }
  if (tg == 1) comb[e4] = a4;
  __syncthreads();
  if (tg == 0) {
    f32x4 r = a4 + comb[e4];
    *(f32x4*)(partial + ((size_t)(b * NCH + chunk)) * E_ + e4 * 4) = r;
    if (tid == 0) mstat[b * NCH + chunk] = m_c;
  }
}

// k3: softmax over T per batch -> weights; also per-b (max, Z)
__global__ __launch_bounds__(256) void k3_softmax(const float* __restrict__ logits,
                                                  float* __restrict__ weights,
                                                  float* __restrict__ mz) {
  __shared__ float red[4];
  const int b = blockIdx.x;
  const int tid = threadIdx.x;
  const float* lg = logits + (size_t)b * T_;
  float v[16];
  float m = -1e30f;
  #pragma unroll
  for (int i = 0; i < 16; ++i) {
    v[i] = lg[tid + i * 256];
    m = fmaxf(m, v[i]);
  }
  #pragma unroll
  for (int d = 1; d < 64; d <<= 1) m = fmaxf(m, __shfl_xor(m, d));
  if ((tid & 63) == 0) red[tid >> 6] = m;
  __syncthreads();
  m = fmaxf(fmaxf(red[0], red[1]), fmaxf(red[2], red[3]));
  __syncthreads();
  float s = 0.0f;
  #pragma unroll
  for (int i = 0; i < 16; ++i) {
    v[i] = __expf(v[i] - m);
    s += v[i];
  }
  #pragma unroll
  for (int d = 1; d < 64; d <<= 1) s += __shfl_xor(s, d);
  if ((tid & 63) == 0) red[tid >> 6] = s;
  __syncthreads();
  s = red[0] + red[1] + red[2] + red[3];
  float inv = 1.0f / s;
  #pragma unroll
  for (int i = 0; i < 16; ++i) weights[(size_t)b * T_ + tid + i * 256] = v[i] * inv;
  if (tid == 0) {
    mz[b * 2] = m;
    mz[b * 2 + 1] = s;
  }
}

// k5: context = sum_c exp(m_c - m_b) * partial[b,c,:] / Z_b
__global__ __launch_bounds__(128) void k5_ctx_final(const float* __restrict__ partial,
                                                    const float* __restrict__ mstat,
                                                    const float* __restrict__ mz,
                                                    float* __restrict__ ctx) {
  __shared__ float sc[NCH];
  const int b = blockIdx.x;
  const int tid = threadIdx.x;
  const float m_b = mz[b * 2];
  const float invZ = 1.0f / mz[b * 2 + 1];
  if (tid < NCH) sc[tid] = __expf(mstat[b * NCH + tid] - m_b);
  __syncthreads();
  const float* pp = partial + (size_t)b * NCH * E_ + tid * 4;
  f32x4 s = {};
  #pragma unroll 8
  for (int c = 0; c < NCH; ++c) s += sc[c] * (*(const f32x4*)(pp + (size_t)c * E_));
  s *= invZ;
  *(f32x4*)(ctx + (size_t)b * E_ + tid * 4) = s;
}

extern "C" void kernel_launch(void* const* d_in, const int* in_sizes, int n_in,
                              void* d_out, int out_size, void* d_ws, size_t ws_size,
                              hipStream_t stream) {
  const float* hidden = (const float*)d_in[0];
  const float* enc = (const float*)d_in[1];
  const float* W_attn = (const float*)d_in[2];
  const float* b_attn = (const float*)d_in[3];
  const float* v_w = (const float*)d_in[4];

  float* out_ctx = (float*)d_out;                  // 64*512
  float* out_w = (float*)d_out + (size_t)B_ * H_;  // 64*4096

  char* ws = (char*)d_ws;
  unsigned short* Wt = (unsigned short*)ws;      // 512 KiB
  float* projb = (float*)(ws + (512 << 10));     // 128 KiB
  float* logits = (float*)(ws + (640 << 10));    // 1 MiB
  float* mstat = (float*)(ws + (1664 << 10));    // 16 KiB (64*64 chunk maxes)
  float* mz = (float*)(ws + (1700 << 10));       // 512 B  (per-b max, Z)
  float* partial = (float*)(ws + (1728 << 10));  // 8 MiB  (64*64*512 fp32)

  k0_transpose<<<dim3(32, 32), dim3(16, 16), 0, stream>>>(W_attn, Wt);
  k1_projb<<<dim3(64, 4), 512, 0, stream>>>(hidden, W_attn, b_attn, projb);
  k2_logits<<<dim3(NCH, B_), 256, 0, stream>>>(enc, Wt, projb, v_w, logits, mstat, partial);
  k3_softmax<<<B_, 256, 0, stream>>>(logits, out_w, mz);
  k5_ctx_final<<<B_, 128, 0, stream>>>(partial, mstat, mz, out_ctx);
}

// Round 8
// 347.526 us; speedup vs baseline: 2.2127x; 1.0744x over previous
//
#include <hip/hip_runtime.h>
#include <hip/hip_bf16.h>

typedef __attribute__((ext_vector_type(4))) float f32x4;
typedef __attribute__((ext_vector_type(8))) short s16x8;

#define B_ 64
#define T_ 4096
#define H_ 512
#define E_ 512
#define BM 64          // T-rows per k2 block (= context chunk)
#define NCH (T_ / BM)  // 64 chunks per batch row

__device__ __forceinline__ short b2s(float x) {
  __hip_bfloat16 h = __float2bfloat16(x);  // RNE; pairs fuse to v_cvt_pk_bf16_f32
  return __builtin_bit_cast(short, h);
}

__device__ __forceinline__ s16x8 cvt8(f32x4 a, f32x4 b) {
  s16x8 r;
  r[0] = b2s(a[0]); r[1] = b2s(a[1]); r[2] = b2s(a[2]); r[3] = b2s(a[3]);
  r[4] = b2s(b[0]); r[5] = b2s(b[1]); r[6] = b2s(b[2]); r[7] = b2s(b[3]);
  return r;
}

__device__ __forceinline__ float fast_tanh(float x) {
  float e;
  asm("v_exp_f32 %0, %1" : "=v"(e) : "v"(x * 2.88539008177792681f));  // 2^(2x/ln2)
  float r;
  asm("v_rcp_f32 %0, %1" : "=v"(r) : "v"(e + 1.0f));
  return 1.0f - 2.0f * r;
}

// k0: W_e (rows 512..1023 of W_attn, [e][h]) -> Wt bf16 [h][e]
__global__ void k0_transpose(const float* __restrict__ W, unsigned short* __restrict__ Wt) {
  __shared__ float tile[16][17];
  int e0 = blockIdx.x * 16, h0 = blockIdx.y * 16;
  int tx = threadIdx.x, ty = threadIdx.y;
  tile[ty][tx] = W[(size_t)(512 + e0 + ty) * H_ + h0 + tx];
  __syncthreads();
  Wt[(size_t)(h0 + ty) * E_ + e0 + tx] = (unsigned short)b2s(tile[tx][ty]);
}

// k1: projb[b][h] = b_attn[h] + sum_e hidden[b][e] * W_attn[e][h]
__global__ __launch_bounds__(512) void k1_projb(const float* __restrict__ hidden,
                                                const float* __restrict__ W,
                                                const float* __restrict__ b_attn,
                                                float* __restrict__ projb) {
  __shared__ float hid_s[H_];
  __shared__ float part[4][128];
  const int b = blockIdx.x, hg = blockIdx.y;
  const int tid = threadIdx.x;
  const int hl = tid & 127, es = tid >> 7;
  hid_s[tid] = hidden[b * H_ + tid];
  __syncthreads();
  const int h = hg * 128 + hl;
  const float* wp = W + (size_t)(es * 128) * H_ + h;
  float s = 0.0f;
  #pragma unroll 8
  for (int e = 0; e < 128; ++e) s = fmaf(hid_s[es * 128 + e], wp[(size_t)e * H_], s);
  part[es][hl] = s;
  __syncthreads();
  if (es == 0)
    projb[b * H_ + h] = b_attn[h] + part[0][hl] + part[1][hl] + part[2][hl] + part[3][hl];
}

// k2: fused logits + chunk-softmax + partial context.
// 256 thr = 4 waves; block = 64T x 512H; wave tile 64T x 128H, acc[4][8]=128 AGPR.
// A (enc, 64x512) converted to bf16 and staged in LDS ONCE for the whole K
// extent (64 KB, XOR-swizzled chunk^=(row&7)). Then the 16-step K-loop has
// ZERO barriers: per step {prefetch af(s+1) 4x ds_read_b128, prefetch B(s+1)
// 8x b128 from L2-resident Wt, 32 MFMA} with ping-pong register sets (all
// indices static). Only counted lgkmcnt/vmcnt waits -> waves drift freely.
__global__ __launch_bounds__(256, 2) void k2_logits(
    const float* __restrict__ enc, const unsigned short* __restrict__ Wt,
    const float* __restrict__ projb, const float* __restrict__ vw,
    float* __restrict__ logits, float* __restrict__ mstat,
    float* __restrict__ partial) {
  __shared__ unsigned short a_s[BM * 512];  // 64 KiB, whole-K A tile
  __shared__ float projb_s[H_];
  __shared__ float vw_s[H_];
  __shared__ float part[BM][4];
  __shared__ float lg_s[BM];
  __shared__ f32x4 comb[128];

  const int b = blockIdx.y;
  const int chunk = blockIdx.x;
  const int t0 = chunk * BM;
  const int tid = threadIdx.x;
  const int lane = tid & 63;
  const int w = tid >> 6;  // wave id = H-slice (0..3)
  const int lr = lane & 15;
  const int lq = lane >> 4;

  projb_s[tid] = projb[b * H_ + tid];
  projb_s[tid + 256] = projb[b * H_ + tid + 256];
  vw_s[tid] = vw[tid];
  vw_s[tid + 256] = vw[tid + 256];

  const size_t row0 = (size_t)b * T_ + t0;

  // ---- fill A tile (once): 4 threads/row, 16 chunks (16B bf16) per thread ----
  {
    const int ra = tid >> 2, ca = tid & 3;
    const float* arow = enc + (row0 + ra) * (size_t)E_;
    unsigned short* adst = &a_s[ra * 512];
    #pragma unroll
    for (int jj = 0; jj < 16; ++jj) {
      const int c = ca + jj * 4;  // 16B chunk 0..63
      f32x4 v0 = *(const f32x4*)(arow + c * 8);
      f32x4 v1 = *(const f32x4*)(arow + c * 8 + 4);
      *(s16x8*)&adst[(c ^ (ra & 7)) * 8] = cvt8(v0, v1);
    }
  }
  __syncthreads();  // the ONLY pre-epilogue barrier

  // B fragment base: lane holds Wt row h = w*128 + nb*16 + lr, k-octet lq
  const unsigned short* wtB = Wt + (size_t)(w * 128 + lr) * E_ + lq * 8;
  // af: row = a*16+lr (row&7 == lr&7), chunk = (s*4+lq) ^ (lr&7)
  const unsigned short* aBase = &a_s[0];

#define LOADB(dst, s)                                                        \
  _Pragma("unroll") for (int nb = 0; nb < 8; ++nb) dst[nb] =                 \
      *(const s16x8*)(wtB + (size_t)nb * 16 * E_ + (s) * 32);
#define LOADA(dst, s)                                                        \
  _Pragma("unroll") for (int a = 0; a < 4; ++a) dst[a] =                     \
      *(const s16x8*)&aBase[(a * 16 + lr) * 512 + (((s) * 4 + lq) ^ (lr & 7)) * 8];
#define MFMA32(af, bf)                                                       \
  __builtin_amdgcn_s_setprio(1);                                             \
  _Pragma("unroll") for (int a = 0; a < 4; ++a)                              \
  _Pragma("unroll") for (int nb = 0; nb < 8; ++nb) acc[a][nb] =              \
      __builtin_amdgcn_mfma_f32_16x16x32_bf16(af[a], bf[nb], acc[a][nb], 0, 0, 0); \
  __builtin_amdgcn_s_setprio(0);

  f32x4 acc[4][8] = {};
  s16x8 bA[8], bB[8], aA[4], aB[4];

  LOADA(aA, 0);
  LOADB(bA, 0);
  #pragma unroll
  for (int p = 0; p < 8; ++p) {
    const int s = 2 * p;
    LOADA(aB, s + 1);  // prefetch next step (counted waits only, no drain)
    LOADB(bB, s + 1);
    MFMA32(aA, bA);
    if (p < 7) {
      LOADA(aA, s + 2);
      LOADB(bA, s + 2);
    }
    MFMA32(aB, bB);
  }
#undef LOADA
#undef LOADB
#undef MFMA32

  // ---- logits: energy = tanh(acc + projb), partial = sum_h energy * vw ----
  #pragma unroll
  for (int a = 0; a < 4; ++a) {
    #pragma unroll
    for (int j = 0; j < 4; ++j) {
      float ssum = 0.0f;
      #pragma unroll
      for (int nb = 0; nb < 8; ++nb) {
        const int h = w * 128 + nb * 16 + lr;  // C/D: col = lane&15
        float x = acc[a][nb][j] + projb_s[h];
        ssum += fast_tanh(x) * vw_s[h];
      }
      ssum += __shfl_xor(ssum, 1);
      ssum += __shfl_xor(ssum, 2);
      ssum += __shfl_xor(ssum, 4);
      ssum += __shfl_xor(ssum, 8);
      if (lr == 0) part[a * 16 + lq * 4 + j][w] = ssum;  // C/D: row = lq*4+j
    }
  }
  __syncthreads();
  if (tid < BM) {
    float l = part[tid][0] + part[tid][1] + part[tid][2] + part[tid][3];
    lg_s[tid] = l;
    logits[(size_t)b * T_ + t0 + tid] = l;
  }
  __syncthreads();

  // ---- chunk softmax numerator + partial context (tile rows are L2-hot) ----
  float m_c = -1e30f;
  #pragma unroll 8
  for (int t = 0; t < BM; ++t) m_c = fmaxf(m_c, lg_s[t]);

  const int e4 = tid & 127;  // f32x4 column
  const int tg = tid >> 7;   // 0..1, 32 t-rows each
  f32x4 a4 = {};
  const float* ep = enc + (row0 + tg * 32) * (size_t)E_ + e4 * 4;
  #pragma unroll 4
  for (int i = 0; i < 32; ++i) {
    float pw = __expf(lg_s[tg * 32 + i] - m_c);
    a4 += pw * (*(const f32x4*)(ep + (size_t)i * E_));
  }
  if (tg == 1) comb[e4] = a4;
  __syncthreads();
  if (tg == 0) {
    f32x4 r = a4 + comb[e4];
    *(f32x4*)(partial + ((size_t)(b * NCH + chunk)) * E_ + e4 * 4) = r;
    if (tid == 0) mstat[b * NCH + chunk] = m_c;
  }
}

// k3: softmax over T per batch -> weights; also per-b (max, Z)
__global__ __launch_bounds__(256) void k3_softmax(const float* __restrict__ logits,
                                                  float* __restrict__ weights,
                                                  float* __restrict__ mz) {
  __shared__ float red[4];
  const int b = blockIdx.x;
  const int tid = threadIdx.x;
  const float* lg = logits + (size_t)b * T_;
  float v[16];
  float m = -1e30f;
  #pragma unroll
  for (int i = 0; i < 16; ++i) {
    v[i] = lg[tid + i * 256];
    m = fmaxf(m, v[i]);
  }
  #pragma unroll
  for (int d = 1; d < 64; d <<= 1) m = fmaxf(m, __shfl_xor(m, d));
  if ((tid & 63) == 0) red[tid >> 6] = m;
  __syncthreads();
  m = fmaxf(fmaxf(red[0], red[1]), fmaxf(red[2], red[3]));
  __syncthreads();
  float s = 0.0f;
  #pragma unroll
  for (int i = 0; i < 16; ++i) {
    v[i] = __expf(v[i] - m);
    s += v[i];
  }
  #pragma unroll
  for (int d = 1; d < 64; d <<= 1) s += __shfl_xor(s, d);
  if ((tid & 63) == 0) red[tid >> 6] = s;
  __syncthreads();
  s = red[0] + red[1] + red[2] + red[3];
  float inv = 1.0f / s;
  #pragma unroll
  for (int i = 0; i < 16; ++i) weights[(size_t)b * T_ + tid + i * 256] = v[i] * inv;
  if (tid == 0) {
    mz[b * 2] = m;
    mz[b * 2 + 1] = s;
  }
}

// k5: context = sum_c exp(m_c - m_b) * partial[b,c,:] / Z_b
__global__ __launch_bounds__(128) void k5_ctx_final(const float* __restrict__ partial,
                                                    const float* __restrict__ mstat,
                                                    const float* __restrict__ mz,
                                                    float* __restrict__ ctx) {
  __shared__ float sc[NCH];
  const int b = blockIdx.x;
  const int tid = threadIdx.x;
  const float m_b = mz[b * 2];
  const float invZ = 1.0f / mz[b * 2 + 1];
  if (tid < NCH) sc[tid] = __expf(mstat[b * NCH + tid] - m_b);
  __syncthreads();
  const float* pp = partial + (size_t)b * NCH * E_ + tid * 4;
  f32x4 s = {};
  #pragma unroll 8
  for (int c = 0; c < NCH; ++c) s += sc[c] * (*(const f32x4*)(pp + (size_t)c * E_));
  s *= invZ;
  *(f32x4*)(ctx + (size_t)b * E_ + tid * 4) = s;
}

extern "C" void kernel_launch(void* const* d_in, const int* in_sizes, int n_in,
                              void* d_out, int out_size, void* d_ws, size_t ws_size,
                              hipStream_t stream) {
  const float* hidden = (const float*)d_in[0];
  const float* enc = (const float*)d_in[1];
  const float* W_attn = (const float*)d_in[2];
  const float* b_attn = (const float*)d_in[3];
  const float* v_w = (const float*)d_in[4];

  float* out_ctx = (float*)d_out;                  // 64*512
  float* out_w = (float*)d_out + (size_t)B_ * H_;  // 64*4096

  char* ws = (char*)d_ws;
  unsigned short* Wt = (unsigned short*)ws;      // 512 KiB
  float* projb = (float*)(ws + (512 << 10));     // 128 KiB
  float* logits = (float*)(ws + (640 << 10));    // 1 MiB
  float* mstat = (float*)(ws + (1664 << 10));    // 16 KiB (64*64 chunk maxes)
  float* mz = (float*)(ws + (1700 << 10));       // 512 B  (per-b max, Z)
  float* partial = (float*)(ws + (1728 << 10));  // 8 MiB  (64*64*512 fp32)

  k0_transpose<<<dim3(32, 32), dim3(16, 16), 0, stream>>>(W_attn, Wt);
  k1_projb<<<dim3(64, 4), 512, 0, stream>>>(hidden, W_attn, b_attn, projb);
  k2_logits<<<dim3(NCH, B_), 256, 0, stream>>>(enc, Wt, projb, v_w, logits, mstat, partial);
  k3_softmax<<<B_, 256, 0, stream>>>(logits, out_w, mz);
  k5_ctx_final<<<B_, 128, 0, stream>>>(partial, mstat, mz, out_ctx);
}

// Round 9
// 288.072 us; speedup vs baseline: 2.6693x; 1.2064x over previous
//
#include <hip/hip_runtime.h>
#include <hip/hip_bf16.h>

typedef __attribute__((ext_vector_type(4))) float f32x4;
typedef __attribute__((ext_vector_type(8))) short s16x8;

#define B_ 64
#define T_ 4096
#define H_ 512
#define E_ 512
#define BM 64          // T-rows per k2 block (= context chunk)
#define NCH (T_ / BM)  // 64 chunks per batch row

__device__ __forceinline__ short b2s(float x) {
  __hip_bfloat16 h = __float2bfloat16(x);  // RNE; pairs fuse to v_cvt_pk_bf16_f32
  return __builtin_bit_cast(short, h);
}

__device__ __forceinline__ s16x8 cvt8(f32x4 a, f32x4 b) {
  s16x8 r;
  r[0] = b2s(a[0]); r[1] = b2s(a[1]); r[2] = b2s(a[2]); r[3] = b2s(a[3]);
  r[4] = b2s(b[0]); r[5] = b2s(b[1]); r[6] = b2s(b[2]); r[7] = b2s(b[3]);
  return r;
}

__device__ __forceinline__ float fast_tanh(float x) {
  float e;
  asm("v_exp_f32 %0, %1" : "=v"(e) : "v"(x * 2.88539008177792681f));  // 2^(2x/ln2)
  float r;
  asm("v_rcp_f32 %0, %1" : "=v"(r) : "v"(e + 1.0f));
  return 1.0f - 2.0f * r;
}

// k0: fragment-major repack of W_e (rows 512..1023 of W_attn):
// WtF[((h16*16 + s)*64 + lane)*8 + e] = bf16(W_attn[512 + s*32 + (lane>>4)*8 + e][h16*16 + (lane&15)])
// => in k2, frag(h16,s) is ONE contiguous 1-KiB block; lane i loads base+i*16B
// (perfectly coalesced, zero address divergence).
__global__ __launch_bounds__(512) void k0_fragpack(const float* __restrict__ W,
                                                   unsigned short* __restrict__ WtF) {
  const int h16 = blockIdx.x;   // 0..31
  const int s = blockIdx.y;     // 0..15
  const int tid = threadIdx.x;  // 0..511
  const int lane = tid >> 3, e = tid & 7;
  const int lr = lane & 15, lq = lane >> 4;
  const int k = s * 32 + lq * 8 + e;
  const int h = h16 * 16 + lr;
  WtF[(size_t)(h16 * 16 + s) * 512 + tid] =
      (unsigned short)b2s(W[(size_t)(512 + k) * H_ + h]);
}

// k1: projb[b][h] = b_attn[h] + sum_e hidden[b][e] * W_attn[e][h]
__global__ __launch_bounds__(512) void k1_projb(const float* __restrict__ hidden,
                                                const float* __restrict__ W,
                                                const float* __restrict__ b_attn,
                                                float* __restrict__ projb) {
  __shared__ float hid_s[H_];
  __shared__ float part[4][128];
  const int b = blockIdx.x, hg = blockIdx.y;
  const int tid = threadIdx.x;
  const int hl = tid & 127, es = tid >> 7;
  hid_s[tid] = hidden[b * H_ + tid];
  __syncthreads();
  const int h = hg * 128 + hl;
  const float* wp = W + (size_t)(es * 128) * H_ + h;
  float s = 0.0f;
  #pragma unroll 8
  for (int e = 0; e < 128; ++e) s = fmaf(hid_s[es * 128 + e], wp[(size_t)e * H_], s);
  part[es][hl] = s;
  __syncthreads();
  if (es == 0)
    projb[b * H_ + h] = b_attn[h] + part[0][hl] + part[1][hl] + part[2][hl] + part[3][hl];
}

// k2: fused logits + chunk-softmax + partial context.
// 256 thr = 4 waves; block = 64T x 512H; wave tile 64T x 128H, acc[4][8]=128 AGPR.
// A (enc, 64x512) converted to bf16 and staged in LDS ONCE for the whole K
// extent (64 KB, XOR-swizzled chunk^=(row&7)). 16-step K-loop, ZERO barriers,
// ping-pong register sets; B now loads from fragment-major WtF: each LOADB is
// one coalesced 1-KiB transaction (lane*16B), no TA address splitting.
__global__ __launch_bounds__(256, 2) void k2_logits(
    const float* __restrict__ enc, const unsigned short* __restrict__ wtF,
    const float* __restrict__ projb, const float* __restrict__ vw,
    float* __restrict__ logits, float* __restrict__ mstat,
    float* __restrict__ partial) {
  __shared__ unsigned short a_s[BM * 512];  // 64 KiB, whole-K A tile
  __shared__ float projb_s[H_];
  __shared__ float vw_s[H_];
  __shared__ float part[BM][4];
  __shared__ float lg_s[BM];
  __shared__ f32x4 comb[128];

  const int b = blockIdx.y;
  const int chunk = blockIdx.x;
  const int t0 = chunk * BM;
  const int tid = threadIdx.x;
  const int lane = tid & 63;
  const int w = tid >> 6;  // wave id = H-slice (0..3)
  const int lr = lane & 15;
  const int lq = lane >> 4;

  projb_s[tid] = projb[b * H_ + tid];
  projb_s[tid + 256] = projb[b * H_ + tid + 256];
  vw_s[tid] = vw[tid];
  vw_s[tid + 256] = vw[tid + 256];

  const size_t row0 = (size_t)b * T_ + t0;

  // ---- fill A tile (once): 4 threads/row, 16 chunks (16B bf16) per thread ----
  {
    const int ra = tid >> 2, ca = tid & 3;
    const float* arow = enc + (row0 + ra) * (size_t)E_;
    unsigned short* adst = &a_s[ra * 512];
    #pragma unroll
    for (int jj = 0; jj < 16; ++jj) {
      const int c = ca + jj * 4;  // 16B chunk 0..63
      f32x4 v0 = *(const f32x4*)(arow + c * 8);
      f32x4 v1 = *(const f32x4*)(arow + c * 8 + 4);
      *(s16x8*)&adst[(c ^ (ra & 7)) * 8] = cvt8(v0, v1);
    }
  }
  __syncthreads();  // the ONLY pre-epilogue barrier

  // B: fragment-major; wave w owns h16 = w*8 + nb (nb=0..7)
  const unsigned short* wtW = wtF + ((size_t)w * 8 * 16) * 512 + (size_t)lane * 8;
  // af: row = a*16+lr (row&7 == lr&7), chunk = (s*4+lq) ^ (lr&7)
  const unsigned short* aBase = &a_s[0];

#define LOADB(dst, s)                                                        \
  _Pragma("unroll") for (int nb = 0; nb < 8; ++nb) dst[nb] =                 \
      *(const s16x8*)(wtW + ((size_t)(nb * 16 + (s)) << 9));
#define LOADA(dst, s)                                                        \
  _Pragma("unroll") for (int a = 0; a < 4; ++a) dst[a] =                     \
      *(const s16x8*)&aBase[(a * 16 + lr) * 512 + (((s) * 4 + lq) ^ (lr & 7)) * 8];
#define MFMA32(af, bf)                                                       \
  __builtin_amdgcn_s_setprio(1);                                             \
  _Pragma("unroll") for (int a = 0; a < 4; ++a)                              \
  _Pragma("unroll") for (int nb = 0; nb < 8; ++nb) acc[a][nb] =              \
      __builtin_amdgcn_mfma_f32_16x16x32_bf16(af[a], bf[nb], acc[a][nb], 0, 0, 0); \
  __builtin_amdgcn_s_setprio(0);

  f32x4 acc[4][8] = {};
  s16x8 bA[8], bB[8], aA[4], aB[4];

  LOADA(aA, 0);
  LOADB(bA, 0);
  #pragma unroll
  for (int p = 0; p < 8; ++p) {
    const int s = 2 * p;
    LOADA(aB, s + 1);  // prefetch next step (counted waits only, no drain)
    LOADB(bB, s + 1);
    MFMA32(aA, bA);
    if (p < 7) {
      LOADA(aA, s + 2);
      LOADB(bA, s + 2);
    }
    MFMA32(aB, bB);
  }
#undef LOADA
#undef LOADB
#undef MFMA32

  // ---- logits: energy = tanh(acc + projb), partial = sum_h energy * vw ----
  #pragma unroll
  for (int a = 0; a < 4; ++a) {
    #pragma unroll
    for (int j = 0; j < 4; ++j) {
      float ssum = 0.0f;
      #pragma unroll
      for (int nb = 0; nb < 8; ++nb) {
        const int h = w * 128 + nb * 16 + lr;  // C/D: col = lane&15
        float x = acc[a][nb][j] + projb_s[h];
        ssum += fast_tanh(x) * vw_s[h];
      }
      ssum += __shfl_xor(ssum, 1);
      ssum += __shfl_xor(ssum, 2);
      ssum += __shfl_xor(ssum, 4);
      ssum += __shfl_xor(ssum, 8);
      if (lr == 0) part[a * 16 + lq * 4 + j][w] = ssum;  // C/D: row = lq*4+j
    }
  }
  __syncthreads();
  if (tid < BM) {
    float l = part[tid][0] + part[tid][1] + part[tid][2] + part[tid][3];
    lg_s[tid] = l;
    logits[(size_t)b * T_ + t0 + tid] = l;
  }
  __syncthreads();

  // ---- chunk softmax numerator + partial context (tile rows are L2-hot) ----
  float m_c = -1e30f;
  #pragma unroll 8
  for (int t = 0; t < BM; ++t) m_c = fmaxf(m_c, lg_s[t]);

  const int e4 = tid & 127;  // f32x4 column
  const int tg = tid >> 7;   // 0..1, 32 t-rows each
  f32x4 a4 = {};
  const float* ep = enc + (row0 + tg * 32) * (size_t)E_ + e4 * 4;
  #pragma unroll 4
  for (int i = 0; i < 32; ++i) {
    float pw = __expf(lg_s[tg * 32 + i] - m_c);
    a4 += pw * (*(const f32x4*)(ep + (size_t)i * E_));
  }
  if (tg == 1) comb[e4] = a4;
  __syncthreads();
  if (tg == 0) {
    f32x4 r = a4 + comb[e4];
    *(f32x4*)(partial + ((size_t)(b * NCH + chunk)) * E_ + e4 * 4) = r;
    if (tid == 0) mstat[b * NCH + chunk] = m_c;
  }
}

// k3: softmax over T per batch -> weights; also per-b (max, Z)
__global__ __launch_bounds__(256) void k3_softmax(const float* __restrict__ logits,
                                                  float* __restrict__ weights,
                                                  float* __restrict__ mz) {
  __shared__ float red[4];
  const int b = blockIdx.x;
  const int tid = threadIdx.x;
  const float* lg = logits + (size_t)b * T_;
  float v[16];
  float m = -1e30f;
  #pragma unroll
  for (int i = 0; i < 16; ++i) {
    v[i] = lg[tid + i * 256];
    m = fmaxf(m, v[i]);
  }
  #pragma unroll
  for (int d = 1; d < 64; d <<= 1) m = fmaxf(m, __shfl_xor(m, d));
  if ((tid & 63) == 0) red[tid >> 6] = m;
  __syncthreads();
  m = fmaxf(fmaxf(red[0], red[1]), fmaxf(red[2], red[3]));
  __syncthreads();
  float s = 0.0f;
  #pragma unroll
  for (int i = 0; i < 16; ++i) {
    v[i] = __expf(v[i] - m);
    s += v[i];
  }
  #pragma unroll
  for (int d = 1; d < 64; d <<= 1) s += __shfl_xor(s, d);
  if ((tid & 63) == 0) red[tid >> 6] = s;
  __syncthreads();
  s = red[0] + red[1] + red[2] + red[3];
  float inv = 1.0f / s;
  #pragma unroll
  for (int i = 0; i < 16; ++i) weights[(size_t)b * T_ + tid + i * 256] = v[i] * inv;
  if (tid == 0) {
    mz[b * 2] = m;
    mz[b * 2 + 1] = s;
  }
}

// k5: context = sum_c exp(m_c - m_b) * partial[b,c,:] / Z_b
__global__ __launch_bounds__(128) void k5_ctx_final(const float* __restrict__ partial,
                                                    const float* __restrict__ mstat,
                                                    const float* __restrict__ mz,
                                                    float* __restrict__ ctx) {
  __shared__ float sc[NCH];
  const int b = blockIdx.x;
  const int tid = threadIdx.x;
  const float m_b = mz[b * 2];
  const float invZ = 1.0f / mz[b * 2 + 1];
  if (tid < NCH) sc[tid] = __expf(mstat[b * NCH + tid] - m_b);
  __syncthreads();
  const float* pp = partial + (size_t)b * NCH * E_ + tid * 4;
  f32x4 s = {};
  #pragma unroll 8
  for (int c = 0; c < NCH; ++c) s += sc[c] * (*(const f32x4*)(pp + (size_t)c * E_));
  s *= invZ;
  *(f32x4*)(ctx + (size_t)b * E_ + tid * 4) = s;
}

extern "C" void kernel_launch(void* const* d_in, const int* in_sizes, int n_in,
                              void* d_out, int out_size, void* d_ws, size_t ws_size,
                              hipStream_t stream) {
  const float* hidden = (const float*)d_in[0];
  const float* enc = (const float*)d_in[1];
  const float* W_attn = (const float*)d_in[2];
  const float* b_attn = (const float*)d_in[3];
  const float* v_w = (const float*)d_in[4];

  float* out_ctx = (float*)d_out;                  // 64*512
  float* out_w = (float*)d_out + (size_t)B_ * H_;  // 64*4096

  char* ws = (char*)d_ws;
  unsigned short* WtF = (unsigned short*)ws;     // 512 KiB (fragment-major)
  float* projb = (float*)(ws + (512 << 10));     // 128 KiB
  float* logits = (float*)(ws + (640 << 10));    // 1 MiB
  float* mstat = (float*)(ws + (1664 << 10));    // 16 KiB (64*64 chunk maxes)
  float* mz = (float*)(ws + (1700 << 10));       // 512 B  (per-b max, Z)
  float* partial = (float*)(ws + (1728 << 10));  // 8 MiB  (64*64*512 fp32)

  k0_fragpack<<<dim3(32, 16), 512, 0, stream>>>(W_attn, WtF);
  k1_projb<<<dim3(64, 4), 512, 0, stream>>>(hidden, W_attn, b_attn, projb);
  k2_logits<<<dim3(NCH, B_), 256, 0, stream>>>(enc, WtF, projb, v_w, logits, mstat, partial);
  k3_softmax<<<B_, 256, 0, stream>>>(logits, out_w, mz);
  k5_ctx_final<<<B_, 128, 0, stream>>>(partial, mstat, mz, out_ctx);
}